// Round 12
// baseline (418.201 us; speedup 1.0000x reference)
//
#include <hip/hip_runtime.h>
#include <hip/hip_bf16.h>

// GCN forward: StandardScaler -> GCNConv(relu) -> GCNConv -> mean-pool -> Linear
// N=20000 nodes, E=160000 edges, D=512 all layers, G=128 graphs.
//
// Structure:
//  - xs = (x-mu)*rstd pre-split ONCE to bf16 hi/lo; GEMM1 = xs@W1 on matrix
//    cores, 3-term split-bf16, reg-staged pipeline
//  - GEMM2 eliminated: out = pool(Agg(g)) @ W2 @ Wlin + (b2@Wlin+blin)
//  - pool(Agg(g)) = diag(1/n) * Cf * g where Cf[128x20000] is the dense
//    pooling+aggregation coefficient matrix (round 12): random gather -> GEMM
//  - partial K-slices of Cf@g alias dead h; xh/xl alias g

#define NN 20000
#define NE 160000
#define DD 512
#define NG 128
#define PKC 160          // K per pgemm chunk (125 chunks * 160 = 20000 exactly)
#define PNC 125

typedef __attribute__((ext_vector_type(8))) short bf16x8;
typedef __attribute__((ext_vector_type(4))) float f32x4;

static __device__ __forceinline__ short f2bf(float f) {
    union { float f; unsigned u; } a; a.f = f;
    unsigned r = a.u + 0x7FFF + ((a.u >> 16) & 1);   // RNE
    return (short)(r >> 16);
}
static __device__ __forceinline__ float bf2f(short s) {
    union { unsigned u; float f; } a; a.u = ((unsigned)(unsigned short)s) << 16;
    return a.f;
}

// ---------------- column stats (mean / rstd) ----------------
__global__ __launch_bounds__(256) void colstats_kernel(const float* __restrict__ x,
                                                       float* __restrict__ colsum,
                                                       float* __restrict__ colsq) {
    int c = blockIdx.x * 256 + threadIdx.x;
    int r0 = blockIdx.y * 100;
    float s = 0.f, sq = 0.f;
    for (int r = r0; r < r0 + 100; ++r) {
        float v = x[(size_t)r * DD + c];
        s += v;
        sq = fmaf(v, v, sq);
    }
    atomicAdd(&colsum[c], s);
    atomicAdd(&colsq[c], sq);
}

__global__ void finalize_kernel(const float* __restrict__ colsum, const float* __restrict__ colsq,
                                float* __restrict__ rstd, float* __restrict__ murs) {
    int c = threadIdx.x;
    float m = colsum[c] * (1.0f / NN);
    float var = colsq[c] * (1.0f / NN) - m * m;
    float sd = sqrtf(fmaxf(var, 0.0f));
    float rs = (sd > 0.0f) ? (1.0f / sd) : 1.0f;
    rstd[c] = rs;
    murs[c] = m * rs;
}

// xs = x*rstd - murs, split to bf16 hi/lo. One float4 per thread.
__global__ __launch_bounds__(256) void xsplit_kernel(const float* __restrict__ x,
                                                     const float* __restrict__ rstd,
                                                     const float* __restrict__ murs,
                                                     short* __restrict__ xh,
                                                     short* __restrict__ xl) {
    int idx = blockIdx.x * 256 + threadIdx.x;
    int c4 = (idx & 127) * 4;
    float4 v = *(const float4*)(x + (size_t)idx * 4);
    float4 rs = *(const float4*)(rstd + c4);
    float4 ms = *(const float4*)(murs + c4);
    float s0 = fmaf(v.x, rs.x, -ms.x), s1 = fmaf(v.y, rs.y, -ms.y);
    float s2 = fmaf(v.z, rs.z, -ms.z), s3 = fmaf(v.w, rs.w, -ms.w);
    short h0 = f2bf(s0), h1 = f2bf(s1), h2 = f2bf(s2), h3 = f2bf(s3);
    *(short4*)(xh + (size_t)idx * 4) = make_short4(h0, h1, h2, h3);
    *(short4*)(xl + (size_t)idx * 4) =
        make_short4(f2bf(s0 - bf2f(h0)), f2bf(s1 - bf2f(h1)),
                    f2bf(s2 - bf2f(h2)), f2bf(s3 - bf2f(h3)));
}

// W^T bf16 split: Wh/Wl[n][k] = split(W1[k][n]); 32x32 LDS tiles
__global__ __launch_bounds__(256) void wsplit_kernel(const float* __restrict__ W1,
                                                     short* __restrict__ Wh,
                                                     short* __restrict__ Wl) {
    __shared__ float t[32][33];
    int bk = blockIdx.x * 32, bn = blockIdx.y * 32;
    int r = threadIdx.x >> 5, c = threadIdx.x & 31;
#pragma unroll
    for (int i = 0; i < 4; ++i) {
        int rr = r + i * 8;
        t[rr][c] = W1[(size_t)(bk + rr) * DD + bn + c];
    }
    __syncthreads();
#pragma unroll
    for (int i = 0; i < 4; ++i) {
        int rr = r + i * 8;
        float v = t[c][rr];
        short h = f2bf(v);
        short l = f2bf(v - bf2f(h));
        Wh[(size_t)(bn + rr) * DD + bk + c] = h;
        Wl[(size_t)(bn + rr) * DD + bk + c] = l;
    }
}

// ---------------- graph structure (CSR by destination) ----------------
__global__ void deginit_kernel(int* __restrict__ deg) {
    int i = blockIdx.x * 256 + threadIdx.x;
    if (i < NN) deg[i] = 1;
}

__global__ void degcount_kernel(const int* __restrict__ dst, int* __restrict__ deg, int es) {
    int e = blockIdx.x * 256 + threadIdx.x;
    if (e < NE) {
        int d = dst[(size_t)e * es];
        if ((unsigned)d < (unsigned)NN) atomicAdd(&deg[d], 1);
    }
}

__global__ void dis_kernel(const int* __restrict__ deg, float* __restrict__ dis) {
    int i = blockIdx.x * 256 + threadIdx.x;
    if (i < NN) dis[i] = rsqrtf((float)deg[i]);
}

// exclusive scan of indeg (deg-1); writes rowptr[0..20000] and cursor copy
__global__ __launch_bounds__(1024) void scan_kernel(const int* __restrict__ deg,
                                                    int* __restrict__ rowptr,
                                                    int* __restrict__ cursor) {
    const int PER = 20;
    __shared__ int sums[1024];
    int t = threadIdx.x;
    int base = t * PER;
    int local[PER];
    int s = 0;
#pragma unroll
    for (int j = 0; j < PER; ++j) {
        int idx = base + j;
        int v = (idx < NN) ? (deg[idx] - 1) : 0;
        local[j] = s;
        s += v;
    }
    sums[t] = s;
    __syncthreads();
    for (int off = 1; off < 1024; off <<= 1) {
        int v = (t >= off) ? sums[t - off] : 0;
        __syncthreads();
        sums[t] += v;
        __syncthreads();
    }
    int prefix = (t == 0) ? 0 : sums[t - 1];
#pragma unroll
    for (int j = 0; j < PER; ++j) {
        int idx = base + j;
        if (idx <= NN) {
            int val = prefix + local[j];
            rowptr[idx] = val;
            if (idx < NN) cursor[idx] = val;
        }
    }
}

__global__ void scatter_kernel(const int* __restrict__ src, const int* __restrict__ dst,
                               int* __restrict__ cursor, int* __restrict__ csrsrc, int es) {
    int e = blockIdx.x * 256 + threadIdx.x;
    if (e < NE) {
        int d = dst[(size_t)e * es];
        int sN = src[(size_t)e * es];
        if ((unsigned)d < (unsigned)NN && (unsigned)sN < (unsigned)NN) {
            int slot = atomicAdd(&cursor[d], 1);
            csrsrc[slot] = sN;
        }
    }
}

// ---------------- pooling coefficient matrix Cf[NG][NN] ----------------
// Cf[batch[j]][j] = d_j^2 ; Cf[batch[i]][s] += d_i*d_s for each edge (s->i).
__global__ void cnode_kernel(const int* __restrict__ batch, int bs,
                             const float* __restrict__ dis, float* __restrict__ Cf) {
    int j = blockIdx.x * 256 + threadIdx.x;
    if (j < NN) {
        int G = batch[(size_t)j * bs];
        if ((unsigned)G < (unsigned)NG) {
            float d = dis[j];
            // node pass runs before edge pass, plain store (cell untouched by others)
            atomicAdd(&Cf[(size_t)G * NN + j], d * d);
        }
    }
}

__global__ void cedge_kernel(const int* __restrict__ src, const int* __restrict__ dst, int es,
                             const int* __restrict__ batch, int bs,
                             const float* __restrict__ dis, float* __restrict__ Cf) {
    int e = blockIdx.x * 256 + threadIdx.x;
    if (e < NE) {
        int i = dst[(size_t)e * es];
        int s = src[(size_t)e * es];
        if ((unsigned)i < (unsigned)NN && (unsigned)s < (unsigned)NN) {
            int G = batch[(size_t)i * bs];
            if ((unsigned)G < (unsigned)NG)
                atomicAdd(&Cf[(size_t)G * NN + s], dis[i] * dis[s]);
        }
    }
}

// inv_n[g] = 1/max(1, #nodes in graph g)  (batch sorted)
__global__ void invn_kernel(const int* __restrict__ batch, int bs, float* __restrict__ inv_n) {
    int g = threadIdx.x;                               // 128 threads
    int lo = 0, hi = NN;
    while (lo < hi) { int m = (lo + hi) >> 1; if (batch[(size_t)m * bs] < g) lo = m + 1; else hi = m; }
    int l0 = lo;
    lo = l0; hi = NN;
    while (lo < hi) { int m = (lo + hi) >> 1; if (batch[(size_t)m * bs] < g + 1) lo = m + 1; else hi = m; }
    inv_n[g] = 1.0f / fmaxf((float)(lo - l0), 1.0f);
}

// ---------------- split-bf16 MFMA GEMM: C[M x 512] = A @ W^T  (A,W pre-split bf16) ------------
// Reg-staged pipeline: load K-tile t+1 into regs while computing tile t.
__global__ __launch_bounds__(256) void gemm_mfma_kernel(const short* __restrict__ Ah_g,
                                                        const short* __restrict__ Al_g,
                                                        const short* __restrict__ Bh_g,
                                                        const short* __restrict__ Bl_g,
                                                        float* __restrict__ C,
                                                        int M) {
    __shared__ __attribute__((aligned(16))) short sAh[128][40];
    __shared__ __attribute__((aligned(16))) short sAl[128][40];
    __shared__ __attribute__((aligned(16))) short sBh[128][40];
    __shared__ __attribute__((aligned(16))) short sBl[128][40];
    int tid = threadIdx.x;
    int wave = tid >> 6, lane = tid & 63;
    int wm = (wave >> 1) * 64, wn = (wave & 1) * 64;
    int rowBase = blockIdx.x * 128, colBase = blockIdx.y * 128;
    int fr = lane & 15, kq = (lane >> 4) * 8;

    int s0 = tid, s1 = tid + 256;
    int r0 = s0 >> 2, k80 = (s0 & 3) * 8;
    int r1 = s1 >> 2, k81 = (s1 & 3) * 8;
    int ga0 = rowBase + r0, ga1 = rowBase + r1;
    int gb0 = colBase + r0, gb1 = colBase + r1;
    const bool av0 = ga0 < M, av1 = ga1 < M;

    f32x4 acc[4][4];
#pragma unroll
    for (int i = 0; i < 4; ++i)
#pragma unroll
        for (int j = 0; j < 4; ++j) acc[i][j] = (f32x4){0.f, 0.f, 0.f, 0.f};

    const bf16x8 z8 = {0, 0, 0, 0, 0, 0, 0, 0};
    bf16x8 rAh0, rAh1, rAl0, rAl1, rBh0, rBh1, rBl0, rBl1;

#define GLOAD(KK)                                                                      \
    do {                                                                               \
        rAh0 = av0 ? *(const bf16x8*)(Ah_g + (size_t)ga0 * DD + (KK) + k80) : z8;      \
        rAl0 = av0 ? *(const bf16x8*)(Al_g + (size_t)ga0 * DD + (KK) + k80) : z8;      \
        rAh1 = av1 ? *(const bf16x8*)(Ah_g + (size_t)ga1 * DD + (KK) + k81) : z8;      \
        rAl1 = av1 ? *(const bf16x8*)(Al_g + (size_t)ga1 * DD + (KK) + k81) : z8;      \
        rBh0 = *(const bf16x8*)(Bh_g + (size_t)gb0 * DD + (KK) + k80);                 \
        rBl0 = *(const bf16x8*)(Bl_g + (size_t)gb0 * DD + (KK) + k80);                 \
        rBh1 = *(const bf16x8*)(Bh_g + (size_t)gb1 * DD + (KK) + k81);                 \
        rBl1 = *(const bf16x8*)(Bl_g + (size_t)gb1 * DD + (KK) + k81);                 \
    } while (0)

    GLOAD(0);
    for (int step = 0; step < 16; ++step) {
        *(bf16x8*)&sAh[r0][k80] = rAh0;  *(bf16x8*)&sAl[r0][k80] = rAl0;
        *(bf16x8*)&sAh[r1][k81] = rAh1;  *(bf16x8*)&sAl[r1][k81] = rAl1;
        *(bf16x8*)&sBh[r0][k80] = rBh0;  *(bf16x8*)&sBl[r0][k80] = rBl0;
        *(bf16x8*)&sBh[r1][k81] = rBh1;  *(bf16x8*)&sBl[r1][k81] = rBl1;
        __syncthreads();
        if (step < 15) GLOAD((step + 1) * 32);

        bf16x8 fah[4], fal[4], fbh[4], fbl[4];
#pragma unroll
        for (int mi = 0; mi < 4; ++mi) {
            fah[mi] = *(const bf16x8*)&sAh[wm + mi * 16 + fr][kq];
            fal[mi] = *(const bf16x8*)&sAl[wm + mi * 16 + fr][kq];
        }
#pragma unroll
        for (int ni = 0; ni < 4; ++ni) {
            fbh[ni] = *(const bf16x8*)&sBh[wn + ni * 16 + fr][kq];
            fbl[ni] = *(const bf16x8*)&sBl[wn + ni * 16 + fr][kq];
        }
#pragma unroll
        for (int mi = 0; mi < 4; ++mi)
#pragma unroll
            for (int ni = 0; ni < 4; ++ni) {
                acc[mi][ni] = __builtin_amdgcn_mfma_f32_16x16x32_bf16(fah[mi], fbh[ni], acc[mi][ni], 0, 0, 0);
                acc[mi][ni] = __builtin_amdgcn_mfma_f32_16x16x32_bf16(fah[mi], fbl[ni], acc[mi][ni], 0, 0, 0);
                acc[mi][ni] = __builtin_amdgcn_mfma_f32_16x16x32_bf16(fal[mi], fbh[ni], acc[mi][ni], 0, 0, 0);
            }
        __syncthreads();
    }
#undef GLOAD

#pragma unroll
    for (int mi = 0; mi < 4; ++mi)
#pragma unroll
        for (int ni = 0; ni < 4; ++ni) {
            int col = colBase + wn + ni * 16 + fr;
            int row0 = rowBase + wm + mi * 16 + (lane >> 4) * 4;
#pragma unroll
            for (int r = 0; r < 4; ++r) {
                int row = row0 + r;
                if (row < M) C[(size_t)row * DD + col] = acc[mi][ni][r];
            }
        }
}

// ---------------- edge aggregation: out[i] = di*(di*h[i] + sum_e dis[s]*h[s]) + b [relu] ----
__global__ __launch_bounds__(256) void agg_kernel(const float* __restrict__ h,
                                                  float* __restrict__ out,
                                                  const float* __restrict__ dis,
                                                  const int* __restrict__ rowptr,
                                                  const int* __restrict__ csrsrc,
                                                  const float* __restrict__ bias,
                                                  int relu) {
    int i = blockIdx.x;
    int f = threadIdx.x * 2;
    float di = dis[i];
    float2 v = *(const float2*)(h + (size_t)i * DD + f);
    float accx = di * v.x, accy = di * v.y;
    int e0 = rowptr[i], e1 = rowptr[i + 1];
    if (e0 < e1) {
        int s = csrsrc[e0];
        float ds = dis[s];
        for (int e = e0; e < e1; ++e) {
            int   sn = 0;
            float dn = 0.f;
            if (e + 1 < e1) { sn = csrsrc[e + 1]; dn = dis[sn]; }
            float2 hv = *(const float2*)(h + (size_t)s * DD + f);
            accx = fmaf(ds, hv.x, accx);
            accy = fmaf(ds, hv.y, accy);
            s = sn; ds = dn;
        }
    }
    accx = fmaf(di, accx, bias[f]);
    accy = fmaf(di, accy, bias[f + 1]);
    if (relu) { accx = fmaxf(accx, 0.f); accy = fmaxf(accy, 0.f); }
    *(float2*)(out + (size_t)i * DD + f) = make_float2(accx, accy);
}

// ---------------- pooling GEMM: part[kc][128][512] = Cf[:, krange] @ g[krange, :] ----------
// Validated round-6 fp32 tile (BM=128,BN=128,BK=16), K-chunked for parallelism.
__global__ __launch_bounds__(256) void pgemm_kernel(const float* __restrict__ A,   // Cf [128][NN]
                                                    const float* __restrict__ B,   // g  [NN][512]
                                                    float* __restrict__ part) {
    __shared__ float As[16][132];                     // transposed A tile, padded
    __shared__ float Bs[16][128];
    int tid = threadIdx.x;
    int tx = tid & 15, ty = tid >> 4;
    int colBase = blockIdx.x * 128;                   // 4 col-blocks
    int kc = blockIdx.y;                              // 125 K-chunks
    int kBase = kc * PKC;

    float acc[8][8];
#pragma unroll
    for (int i = 0; i < 8; ++i)
#pragma unroll
        for (int j = 0; j < 8; ++j) acc[i][j] = 0.f;

    for (int k0 = kBase; k0 < kBase + PKC; k0 += 16) {
#pragma unroll
        for (int i = 0; i < 2; ++i) {                 // A tile: rows=G(128) x k(16)
            int lin = tid + i * 256;
            int r = lin >> 2, c4 = (lin & 3) * 4;
            float4 v = *(const float4*)(A + (size_t)r * NN + k0 + c4);
            As[c4 + 0][r] = v.x;
            As[c4 + 1][r] = v.y;
            As[c4 + 2][r] = v.z;
            As[c4 + 3][r] = v.w;
        }
#pragma unroll
        for (int i = 0; i < 2; ++i) {                 // B tile: k(16) x cols(128)
            int lin = tid + i * 256;
            int kk = lin >> 5, c4 = (lin & 31) * 4;
            *(float4*)&Bs[kk][c4] = *(const float4*)(B + (size_t)(k0 + kk) * DD + colBase + c4);
        }
        __syncthreads();
#pragma unroll
        for (int kk = 0; kk < 16; ++kk) {
            float a[8], b[8];
            *(float4*)&a[0] = *(const float4*)&As[kk][ty * 4];
            *(float4*)&a[4] = *(const float4*)&As[kk][64 + ty * 4];
            *(float4*)&b[0] = *(const float4*)&Bs[kk][tx * 4];
            *(float4*)&b[4] = *(const float4*)&Bs[kk][64 + tx * 4];
#pragma unroll
            for (int i = 0; i < 8; ++i)
#pragma unroll
                for (int j = 0; j < 8; ++j) acc[i][j] = fmaf(a[i], b[j], acc[i][j]);
        }
        __syncthreads();
    }

    float* dst = part + (size_t)kc * NG * DD;
#pragma unroll
    for (int i = 0; i < 8; ++i) {
        int r = (i < 4) ? (ty * 4 + i) : (64 + ty * 4 + (i - 4));
        int c0 = colBase + tx * 4;
        int c1c = colBase + 64 + tx * 4;
        *(float4*)(dst + (size_t)r * DD + c0) =
            make_float4(acc[i][0], acc[i][1], acc[i][2], acc[i][3]);
        *(float4*)(dst + (size_t)r * DD + c1c) =
            make_float4(acc[i][4], acc[i][5], acc[i][6], acc[i][7]);
    }
}

// ---------------- small dense tail: dst[128x512] = (scale_g * sum_sl src[sl]) @ W + bias ----
__global__ __launch_bounds__(256) void final_kernel(const float* __restrict__ src, int nslice,
                                                    const float* __restrict__ W,
                                                    const float* __restrict__ bias,
                                                    float* __restrict__ dst,
                                                    const float* __restrict__ scale) {
    __shared__ float p[DD];
    int g = blockIdx.x;
    int t = threadIdx.x;
    float s0 = 0.f, s1 = 0.f;
    for (int sl = 0; sl < nslice; ++sl) {
        s0 += src[((size_t)sl * NG + g) * DD + t];
        s1 += src[((size_t)sl * NG + g) * DD + t + 256];
    }
    float sc = scale ? scale[g] : 1.0f;
    p[t] = s0 * sc;
    p[t + 256] = s1 * sc;
    __syncthreads();
    float a0 = bias[t], a1 = bias[t + 256];
    for (int k = 0; k < DD; ++k) {
        float pk = p[k];
        a0 = fmaf(pk, W[(size_t)k * DD + t], a0);
        a1 = fmaf(pk, W[(size_t)k * DD + t + 256], a1);
    }
    dst[(size_t)g * DD + t] = a0;
    dst[(size_t)g * DD + t + 256] = a1;
}

// ---------------- launch ----------------
extern "C" void kernel_launch(void* const* d_in, const int* in_sizes, int n_in,
                              void* d_out, int out_size, void* d_ws, size_t ws_size,
                              hipStream_t stream) {
    const float* x    = (const float*)d_in[0];
    const int*   ei   = (const int*)d_in[1];
    const int*   batch= (const int*)d_in[2];
    const float* W1   = (const float*)d_in[3];
    const float* b1   = (const float*)d_in[4];
    const float* W2   = (const float*)d_in[5];
    const float* b2   = (const float*)d_in[6];
    const float* Wlin = (const float*)d_in[7];
    const float* blin = (const float*)d_in[8];
    float* out = (float*)d_out;

    const int es = (in_sizes[1] == 2 * 2 * NE) ? 2 : 1;
    const int bs = (in_sizes[2] == 2 * NN) ? 2 : 1;
    const int* esrc = ei;
    const int* edst = ei + (size_t)NE * es;

    char* w = (char*)d_ws;
    auto alloc = [&](size_t bytes) { void* p = (void*)w; w += (bytes + 255) & ~(size_t)255; return p; };
    float* h      = (float*)alloc((size_t)NN * DD * 4);   // GEMM1 out; dead after agg ->
    float* part   = h;                                    //   pgemm partials [125][128][512] = 33MB
    float* g      = (float*)alloc((size_t)NN * DD * 4);   // conv1 out; before agg,
    short* xh     = (short*)g;                            //   aliased as xs bf16 hi
    short* xl     = (short*)g + (size_t)NN * DD;          //   and lo - dead after gemm
    short* W1h    = (short*)alloc((size_t)DD * DD * 2);
    short* W1l    = (short*)alloc((size_t)DD * DD * 2);
    float* Cf     = (float*)alloc((size_t)NG * NN * 4);   // pooling coeff matrix, 10.24MB
    float* tbuf   = (float*)alloc((size_t)NG * DD * 4);
    float* inv_n  = (float*)alloc(NG * 4);
    float* rstd   = (float*)alloc(DD * 4);
    float* murs   = (float*)alloc(DD * 4);
    float* stats  = (float*)alloc(2 * DD * 4);
    float* dis    = (float*)alloc(NN * 4);
    int*   deg    = (int*)alloc(NN * 4);
    int*   rowptr = (int*)alloc((NN + 4) * 4);
    int*   cursor = (int*)alloc(NN * 4);
    int*   csrsrc = (int*)alloc(NE * 4);
    float* colsum = stats;
    float* colsq  = stats + DD;

    // scaler stats -> rstd, mu*rstd; standardize+split x, split W1^T
    hipMemsetAsync(stats, 0, 2 * DD * 4, stream);
    colstats_kernel<<<dim3(2, 200), 256, 0, stream>>>(x, colsum, colsq);
    finalize_kernel<<<1, 512, 0, stream>>>(colsum, colsq, rstd, murs);
    xsplit_kernel<<<10000, 256, 0, stream>>>(x, rstd, murs, xh, xl);
    wsplit_kernel<<<dim3(16, 16), 256, 0, stream>>>(W1, W1h, W1l);

    // graph structure
    deginit_kernel<<<(NN + 255) / 256, 256, 0, stream>>>(deg);
    degcount_kernel<<<NE / 256, 256, 0, stream>>>(edst, deg, es);
    dis_kernel<<<(NN + 255) / 256, 256, 0, stream>>>(deg, dis);
    scan_kernel<<<1, 1024, 0, stream>>>(deg, rowptr, cursor);
    scatter_kernel<<<NE / 256, 256, 0, stream>>>(esrc, edst, cursor, csrsrc, es);

    // pooling coefficient matrix + inv counts
    hipMemsetAsync(Cf, 0, (size_t)NG * NN * 4, stream);
    cnode_kernel<<<(NN + 255) / 256, 256, 0, stream>>>(batch, bs, dis, Cf);
    cedge_kernel<<<NE / 256, 256, 0, stream>>>(esrc, edst, es, batch, bs, dis, Cf);
    invn_kernel<<<1, NG, 0, stream>>>(batch, bs, inv_n);

    // conv1: h = xs @ W1 via split-bf16 MFMA (pipelined), then aggregate + b1 + relu -> g
    gemm_mfma_kernel<<<dim3((NN + 127) / 128, DD / 128), 256, 0, stream>>>(xh, xl, W1h, W1l, h, NN);
    agg_kernel<<<NN, 256, 0, stream>>>(h, g, dis, rowptr, csrsrc, b1, 1);
    // conv2+pool: pooled = diag(inv_n) * Cf @ g, as K-chunked streaming GEMM
    pgemm_kernel<<<dim3(4, PNC), 256, 0, stream>>>(Cf, g, part);
    // tail: out = ((pooled @ W2 + b2) @ Wlin + blin)
    final_kernel<<<NG, 256, 0, stream>>>(part, PNC, W2, b2, tbuf, inv_n);
    final_kernel<<<NG, 256, 0, stream>>>(tbuf, 1, Wlin, blin, out, nullptr);
}

// Round 13
// 352.249 us; speedup vs baseline: 1.1872x; 1.1872x over previous
//
#include <hip/hip_runtime.h>
#include <hip/hip_bf16.h>

// GCN forward: StandardScaler -> GCNConv(relu) -> GCNConv -> mean-pool -> Linear
// N=20000 nodes, E=160000 edges, D=512 all layers, G=128 graphs.
//
// Structure:
//  - xs = (x-mu)*rstd pre-split ONCE to bf16 hi/lo; GEMM1 = xs@W1 on matrix
//    cores, 3-term split-bf16, reg-staged pipeline
//  - GEMM2 eliminated: out = pool(Agg(g)) @ W2 @ Wlin + (b2@Wlin+blin)
//  - pool(Agg(g)) = diag(1/n) * Cf * g with dense Cf[128x20000] (gather -> GEMM)
//  - round 13: tail parallelized - reduce(125 slices) 1024-blk streaming kernel,
//    then two (128x8)-block K-split GEMMs (old 128-blk final_kernel was 64us
//    latency-bound at 5% occupancy)

#define NN 20000
#define NE 160000
#define DD 512
#define NG 128
#define PKC 160          // K per pgemm chunk (125 chunks * 160 = 20000 exactly)
#define PNC 125

typedef __attribute__((ext_vector_type(8))) short bf16x8;
typedef __attribute__((ext_vector_type(4))) float f32x4;

static __device__ __forceinline__ short f2bf(float f) {
    union { float f; unsigned u; } a; a.f = f;
    unsigned r = a.u + 0x7FFF + ((a.u >> 16) & 1);   // RNE
    return (short)(r >> 16);
}
static __device__ __forceinline__ float bf2f(short s) {
    union { unsigned u; float f; } a; a.u = ((unsigned)(unsigned short)s) << 16;
    return a.f;
}

// ---------------- column stats (mean / rstd) ----------------
__global__ __launch_bounds__(256) void colstats_kernel(const float* __restrict__ x,
                                                       float* __restrict__ colsum,
                                                       float* __restrict__ colsq) {
    int c = blockIdx.x * 256 + threadIdx.x;
    int r0 = blockIdx.y * 100;
    float s = 0.f, sq = 0.f;
    for (int r = r0; r < r0 + 100; ++r) {
        float v = x[(size_t)r * DD + c];
        s += v;
        sq = fmaf(v, v, sq);
    }
    atomicAdd(&colsum[c], s);
    atomicAdd(&colsq[c], sq);
}

__global__ void finalize_kernel(const float* __restrict__ colsum, const float* __restrict__ colsq,
                                float* __restrict__ rstd, float* __restrict__ murs) {
    int c = threadIdx.x;
    float m = colsum[c] * (1.0f / NN);
    float var = colsq[c] * (1.0f / NN) - m * m;
    float sd = sqrtf(fmaxf(var, 0.0f));
    float rs = (sd > 0.0f) ? (1.0f / sd) : 1.0f;
    rstd[c] = rs;
    murs[c] = m * rs;
}

// xs = x*rstd - murs, split to bf16 hi/lo. One float4 per thread.
__global__ __launch_bounds__(256) void xsplit_kernel(const float* __restrict__ x,
                                                     const float* __restrict__ rstd,
                                                     const float* __restrict__ murs,
                                                     short* __restrict__ xh,
                                                     short* __restrict__ xl) {
    int idx = blockIdx.x * 256 + threadIdx.x;
    int c4 = (idx & 127) * 4;
    float4 v = *(const float4*)(x + (size_t)idx * 4);
    float4 rs = *(const float4*)(rstd + c4);
    float4 ms = *(const float4*)(murs + c4);
    float s0 = fmaf(v.x, rs.x, -ms.x), s1 = fmaf(v.y, rs.y, -ms.y);
    float s2 = fmaf(v.z, rs.z, -ms.z), s3 = fmaf(v.w, rs.w, -ms.w);
    short h0 = f2bf(s0), h1 = f2bf(s1), h2 = f2bf(s2), h3 = f2bf(s3);
    *(short4*)(xh + (size_t)idx * 4) = make_short4(h0, h1, h2, h3);
    *(short4*)(xl + (size_t)idx * 4) =
        make_short4(f2bf(s0 - bf2f(h0)), f2bf(s1 - bf2f(h1)),
                    f2bf(s2 - bf2f(h2)), f2bf(s3 - bf2f(h3)));
}

// W^T bf16 split: Wh/Wl[n][k] = split(W1[k][n]); 32x32 LDS tiles
__global__ __launch_bounds__(256) void wsplit_kernel(const float* __restrict__ W1,
                                                     short* __restrict__ Wh,
                                                     short* __restrict__ Wl) {
    __shared__ float t[32][33];
    int bk = blockIdx.x * 32, bn = blockIdx.y * 32;
    int r = threadIdx.x >> 5, c = threadIdx.x & 31;
#pragma unroll
    for (int i = 0; i < 4; ++i) {
        int rr = r + i * 8;
        t[rr][c] = W1[(size_t)(bk + rr) * DD + bn + c];
    }
    __syncthreads();
#pragma unroll
    for (int i = 0; i < 4; ++i) {
        int rr = r + i * 8;
        float v = t[c][rr];
        short h = f2bf(v);
        short l = f2bf(v - bf2f(h));
        Wh[(size_t)(bn + rr) * DD + bk + c] = h;
        Wl[(size_t)(bn + rr) * DD + bk + c] = l;
    }
}

// ---------------- graph structure (CSR by destination) ----------------
__global__ void deginit_kernel(int* __restrict__ deg) {
    int i = blockIdx.x * 256 + threadIdx.x;
    if (i < NN) deg[i] = 1;
}

__global__ void degcount_kernel(const int* __restrict__ dst, int* __restrict__ deg, int es) {
    int e = blockIdx.x * 256 + threadIdx.x;
    if (e < NE) {
        int d = dst[(size_t)e * es];
        if ((unsigned)d < (unsigned)NN) atomicAdd(&deg[d], 1);
    }
}

__global__ void dis_kernel(const int* __restrict__ deg, float* __restrict__ dis) {
    int i = blockIdx.x * 256 + threadIdx.x;
    if (i < NN) dis[i] = rsqrtf((float)deg[i]);
}

// exclusive scan of indeg (deg-1); writes rowptr[0..20000] and cursor copy
__global__ __launch_bounds__(1024) void scan_kernel(const int* __restrict__ deg,
                                                    int* __restrict__ rowptr,
                                                    int* __restrict__ cursor) {
    const int PER = 20;
    __shared__ int sums[1024];
    int t = threadIdx.x;
    int base = t * PER;
    int local[PER];
    int s = 0;
#pragma unroll
    for (int j = 0; j < PER; ++j) {
        int idx = base + j;
        int v = (idx < NN) ? (deg[idx] - 1) : 0;
        local[j] = s;
        s += v;
    }
    sums[t] = s;
    __syncthreads();
    for (int off = 1; off < 1024; off <<= 1) {
        int v = (t >= off) ? sums[t - off] : 0;
        __syncthreads();
        sums[t] += v;
        __syncthreads();
    }
    int prefix = (t == 0) ? 0 : sums[t - 1];
#pragma unroll
    for (int j = 0; j < PER; ++j) {
        int idx = base + j;
        if (idx <= NN) {
            int val = prefix + local[j];
            rowptr[idx] = val;
            if (idx < NN) cursor[idx] = val;
        }
    }
}

__global__ void scatter_kernel(const int* __restrict__ src, const int* __restrict__ dst,
                               int* __restrict__ cursor, int* __restrict__ csrsrc, int es) {
    int e = blockIdx.x * 256 + threadIdx.x;
    if (e < NE) {
        int d = dst[(size_t)e * es];
        int sN = src[(size_t)e * es];
        if ((unsigned)d < (unsigned)NN && (unsigned)sN < (unsigned)NN) {
            int slot = atomicAdd(&cursor[d], 1);
            csrsrc[slot] = sN;
        }
    }
}

// ---------------- pooling coefficient matrix Cf[NG][NN] ----------------
__global__ void cnode_kernel(const int* __restrict__ batch, int bs,
                             const float* __restrict__ dis, float* __restrict__ Cf) {
    int j = blockIdx.x * 256 + threadIdx.x;
    if (j < NN) {
        int G = batch[(size_t)j * bs];
        if ((unsigned)G < (unsigned)NG) {
            float d = dis[j];
            atomicAdd(&Cf[(size_t)G * NN + j], d * d);
        }
    }
}

__global__ void cedge_kernel(const int* __restrict__ src, const int* __restrict__ dst, int es,
                             const int* __restrict__ batch, int bs,
                             const float* __restrict__ dis, float* __restrict__ Cf) {
    int e = blockIdx.x * 256 + threadIdx.x;
    if (e < NE) {
        int i = dst[(size_t)e * es];
        int s = src[(size_t)e * es];
        if ((unsigned)i < (unsigned)NN && (unsigned)s < (unsigned)NN) {
            int G = batch[(size_t)i * bs];
            if ((unsigned)G < (unsigned)NG)
                atomicAdd(&Cf[(size_t)G * NN + s], dis[i] * dis[s]);
        }
    }
}

// inv_n[g] = 1/max(1, #nodes in graph g)  (batch sorted)
__global__ void invn_kernel(const int* __restrict__ batch, int bs, float* __restrict__ inv_n) {
    int g = threadIdx.x;
    int lo = 0, hi = NN;
    while (lo < hi) { int m = (lo + hi) >> 1; if (batch[(size_t)m * bs] < g) lo = m + 1; else hi = m; }
    int l0 = lo;
    lo = l0; hi = NN;
    while (lo < hi) { int m = (lo + hi) >> 1; if (batch[(size_t)m * bs] < g + 1) lo = m + 1; else hi = m; }
    inv_n[g] = 1.0f / fmaxf((float)(lo - l0), 1.0f);
}

// ---------------- split-bf16 MFMA GEMM: C[M x 512] = A @ W^T ----------------
__global__ __launch_bounds__(256) void gemm_mfma_kernel(const short* __restrict__ Ah_g,
                                                        const short* __restrict__ Al_g,
                                                        const short* __restrict__ Bh_g,
                                                        const short* __restrict__ Bl_g,
                                                        float* __restrict__ C,
                                                        int M) {
    __shared__ __attribute__((aligned(16))) short sAh[128][40];
    __shared__ __attribute__((aligned(16))) short sAl[128][40];
    __shared__ __attribute__((aligned(16))) short sBh[128][40];
    __shared__ __attribute__((aligned(16))) short sBl[128][40];
    int tid = threadIdx.x;
    int wave = tid >> 6, lane = tid & 63;
    int wm = (wave >> 1) * 64, wn = (wave & 1) * 64;
    int rowBase = blockIdx.x * 128, colBase = blockIdx.y * 128;
    int fr = lane & 15, kq = (lane >> 4) * 8;

    int s0 = tid, s1 = tid + 256;
    int r0 = s0 >> 2, k80 = (s0 & 3) * 8;
    int r1 = s1 >> 2, k81 = (s1 & 3) * 8;
    int ga0 = rowBase + r0, ga1 = rowBase + r1;
    int gb0 = colBase + r0, gb1 = colBase + r1;
    const bool av0 = ga0 < M, av1 = ga1 < M;

    f32x4 acc[4][4];
#pragma unroll
    for (int i = 0; i < 4; ++i)
#pragma unroll
        for (int j = 0; j < 4; ++j) acc[i][j] = (f32x4){0.f, 0.f, 0.f, 0.f};

    const bf16x8 z8 = {0, 0, 0, 0, 0, 0, 0, 0};
    bf16x8 rAh0, rAh1, rAl0, rAl1, rBh0, rBh1, rBl0, rBl1;

#define GLOAD(KK)                                                                      \
    do {                                                                               \
        rAh0 = av0 ? *(const bf16x8*)(Ah_g + (size_t)ga0 * DD + (KK) + k80) : z8;      \
        rAl0 = av0 ? *(const bf16x8*)(Al_g + (size_t)ga0 * DD + (KK) + k80) : z8;      \
        rAh1 = av1 ? *(const bf16x8*)(Ah_g + (size_t)ga1 * DD + (KK) + k81) : z8;      \
        rAl1 = av1 ? *(const bf16x8*)(Al_g + (size_t)ga1 * DD + (KK) + k81) : z8;      \
        rBh0 = *(const bf16x8*)(Bh_g + (size_t)gb0 * DD + (KK) + k80);                 \
        rBl0 = *(const bf16x8*)(Bl_g + (size_t)gb0 * DD + (KK) + k80);                 \
        rBh1 = *(const bf16x8*)(Bh_g + (size_t)gb1 * DD + (KK) + k81);                 \
        rBl1 = *(const bf16x8*)(Bl_g + (size_t)gb1 * DD + (KK) + k81);                 \
    } while (0)

    GLOAD(0);
    for (int step = 0; step < 16; ++step) {
        *(bf16x8*)&sAh[r0][k80] = rAh0;  *(bf16x8*)&sAl[r0][k80] = rAl0;
        *(bf16x8*)&sAh[r1][k81] = rAh1;  *(bf16x8*)&sAl[r1][k81] = rAl1;
        *(bf16x8*)&sBh[r0][k80] = rBh0;  *(bf16x8*)&sBl[r0][k80] = rBl0;
        *(bf16x8*)&sBh[r1][k81] = rBh1;  *(bf16x8*)&sBl[r1][k81] = rBl1;
        __syncthreads();
        if (step < 15) GLOAD((step + 1) * 32);

        bf16x8 fah[4], fal[4], fbh[4], fbl[4];
#pragma unroll
        for (int mi = 0; mi < 4; ++mi) {
            fah[mi] = *(const bf16x8*)&sAh[wm + mi * 16 + fr][kq];
            fal[mi] = *(const bf16x8*)&sAl[wm + mi * 16 + fr][kq];
        }
#pragma unroll
        for (int ni = 0; ni < 4; ++ni) {
            fbh[ni] = *(const bf16x8*)&sBh[wn + ni * 16 + fr][kq];
            fbl[ni] = *(const bf16x8*)&sBl[wn + ni * 16 + fr][kq];
        }
#pragma unroll
        for (int mi = 0; mi < 4; ++mi)
#pragma unroll
            for (int ni = 0; ni < 4; ++ni) {
                acc[mi][ni] = __builtin_amdgcn_mfma_f32_16x16x32_bf16(fah[mi], fbh[ni], acc[mi][ni], 0, 0, 0);
                acc[mi][ni] = __builtin_amdgcn_mfma_f32_16x16x32_bf16(fah[mi], fbl[ni], acc[mi][ni], 0, 0, 0);
                acc[mi][ni] = __builtin_amdgcn_mfma_f32_16x16x32_bf16(fal[mi], fbh[ni], acc[mi][ni], 0, 0, 0);
            }
        __syncthreads();
    }
#undef GLOAD

#pragma unroll
    for (int mi = 0; mi < 4; ++mi)
#pragma unroll
        for (int ni = 0; ni < 4; ++ni) {
            int col = colBase + wn + ni * 16 + fr;
            int row0 = rowBase + wm + mi * 16 + (lane >> 4) * 4;
#pragma unroll
            for (int r = 0; r < 4; ++r) {
                int row = row0 + r;
                if (row < M) C[(size_t)row * DD + col] = acc[mi][ni][r];
            }
        }
}

// ---------------- edge aggregation: out[i] = di*(di*h[i] + sum_e dis[s]*h[s]) + b [relu] ----
__global__ __launch_bounds__(256) void agg_kernel(const float* __restrict__ h,
                                                  float* __restrict__ out,
                                                  const float* __restrict__ dis,
                                                  const int* __restrict__ rowptr,
                                                  const int* __restrict__ csrsrc,
                                                  const float* __restrict__ bias,
                                                  int relu) {
    int i = blockIdx.x;
    int f = threadIdx.x * 2;
    float di = dis[i];
    float2 v = *(const float2*)(h + (size_t)i * DD + f);
    float accx = di * v.x, accy = di * v.y;
    int e0 = rowptr[i], e1 = rowptr[i + 1];
    if (e0 < e1) {
        int s = csrsrc[e0];
        float ds = dis[s];
        for (int e = e0; e < e1; ++e) {
            int   sn = 0;
            float dn = 0.f;
            if (e + 1 < e1) { sn = csrsrc[e + 1]; dn = dis[sn]; }
            float2 hv = *(const float2*)(h + (size_t)s * DD + f);
            accx = fmaf(ds, hv.x, accx);
            accy = fmaf(ds, hv.y, accy);
            s = sn; ds = dn;
        }
    }
    accx = fmaf(di, accx, bias[f]);
    accy = fmaf(di, accy, bias[f + 1]);
    if (relu) { accx = fmaxf(accx, 0.f); accy = fmaxf(accy, 0.f); }
    *(float2*)(out + (size_t)i * DD + f) = make_float2(accx, accy);
}

// ---------------- pooling GEMM: part[kc][128][512] = Cf[:, krange] @ g[krange, :] ----------
__global__ __launch_bounds__(256) void pgemm_kernel(const float* __restrict__ A,   // Cf [128][NN]
                                                    const float* __restrict__ B,   // g  [NN][512]
                                                    float* __restrict__ part) {
    __shared__ float As[16][132];
    __shared__ float Bs[16][128];
    int tid = threadIdx.x;
    int tx = tid & 15, ty = tid >> 4;
    int colBase = blockIdx.x * 128;
    int kc = blockIdx.y;
    int kBase = kc * PKC;

    float acc[8][8];
#pragma unroll
    for (int i = 0; i < 8; ++i)
#pragma unroll
        for (int j = 0; j < 8; ++j) acc[i][j] = 0.f;

    for (int k0 = kBase; k0 < kBase + PKC; k0 += 16) {
#pragma unroll
        for (int i = 0; i < 2; ++i) {
            int lin = tid + i * 256;
            int r = lin >> 2, c4 = (lin & 3) * 4;
            float4 v = *(const float4*)(A + (size_t)r * NN + k0 + c4);
            As[c4 + 0][r] = v.x;
            As[c4 + 1][r] = v.y;
            As[c4 + 2][r] = v.z;
            As[c4 + 3][r] = v.w;
        }
#pragma unroll
        for (int i = 0; i < 2; ++i) {
            int lin = tid + i * 256;
            int kk = lin >> 5, c4 = (lin & 31) * 4;
            *(float4*)&Bs[kk][c4] = *(const float4*)(B + (size_t)(k0 + kk) * DD + colBase + c4);
        }
        __syncthreads();
#pragma unroll
        for (int kk = 0; kk < 16; ++kk) {
            float a[8], b[8];
            *(float4*)&a[0] = *(const float4*)&As[kk][ty * 4];
            *(float4*)&a[4] = *(const float4*)&As[kk][64 + ty * 4];
            *(float4*)&b[0] = *(const float4*)&Bs[kk][tx * 4];
            *(float4*)&b[4] = *(const float4*)&Bs[kk][64 + tx * 4];
#pragma unroll
            for (int i = 0; i < 8; ++i)
#pragma unroll
                for (int j = 0; j < 8; ++j) acc[i][j] = fmaf(a[i], b[j], acc[i][j]);
        }
        __syncthreads();
    }

    float* dst = part + (size_t)kc * NG * DD;
#pragma unroll
    for (int i = 0; i < 8; ++i) {
        int r = (i < 4) ? (ty * 4 + i) : (64 + ty * 4 + (i - 4));
        int c0 = colBase + tx * 4;
        int c1c = colBase + 64 + tx * 4;
        *(float4*)(dst + (size_t)r * DD + c0) =
            make_float4(acc[i][0], acc[i][1], acc[i][2], acc[i][3]);
        *(float4*)(dst + (size_t)r * DD + c1c) =
            make_float4(acc[i][4], acc[i][5], acc[i][6], acc[i][7]);
    }
}

// ---------------- slice reduce: pooled[e] = inv_n[g] * sum_sl part[sl][e] ----------------
__global__ __launch_bounds__(64) void reduce_kernel(const float* __restrict__ part,
                                                    const float* __restrict__ inv_n,
                                                    float* __restrict__ pooled) {
    int e = blockIdx.x * 64 + threadIdx.x;            // 65536 elements, 1024 blocks
    float s = 0.f;
#pragma unroll 5
    for (int sl = 0; sl < PNC; ++sl)
        s += part[(size_t)sl * (NG * DD) + e];
    pooled[e] = s * inv_n[e >> 9];
}

// ---------------- tail GEMM: dst[g][col] = sum_k src[g][k]*W[k][col] + bias[col] ----------
// Grid (128 g, 8 col-chunks of 64); 256 thr = 64 cols x 4 K-segments; LDS reduce.
__global__ __launch_bounds__(256) void tail_kernel(const float* __restrict__ src,  // [NG][DD]
                                                   const float* __restrict__ W,    // [DD][DD]
                                                   const float* __restrict__ bias,
                                                   float* __restrict__ dst) {
    __shared__ float p[DD];
    __shared__ float red[4][64];
    int g = blockIdx.x;
    int colBase = blockIdx.y * 64;
    int tid = threadIdx.x;
    int c = tid & 63, ks = tid >> 6;
    p[tid] = src[(size_t)g * DD + tid];
    p[tid + 256] = src[(size_t)g * DD + tid + 256];
    __syncthreads();
    int col = colBase + c;
    float acc = 0.f;
    int k0 = ks * 128;
#pragma unroll 8
    for (int k = k0; k < k0 + 128; ++k)
        acc = fmaf(p[k], W[(size_t)k * DD + col], acc);    // p[k] wave-broadcast, W coalesced
    red[ks][c] = acc;
    __syncthreads();
    if (ks == 0)
        dst[(size_t)g * DD + col] = red[0][c] + red[1][c] + red[2][c] + red[3][c] + bias[col];
}

// ---------------- launch ----------------
extern "C" void kernel_launch(void* const* d_in, const int* in_sizes, int n_in,
                              void* d_out, int out_size, void* d_ws, size_t ws_size,
                              hipStream_t stream) {
    const float* x    = (const float*)d_in[0];
    const int*   ei   = (const int*)d_in[1];
    const int*   batch= (const int*)d_in[2];
    const float* W1   = (const float*)d_in[3];
    const float* b1   = (const float*)d_in[4];
    const float* W2   = (const float*)d_in[5];
    const float* b2   = (const float*)d_in[6];
    const float* Wlin = (const float*)d_in[7];
    const float* blin = (const float*)d_in[8];
    float* out = (float*)d_out;

    const int es = (in_sizes[1] == 2 * 2 * NE) ? 2 : 1;
    const int bs = (in_sizes[2] == 2 * NN) ? 2 : 1;
    const int* esrc = ei;
    const int* edst = ei + (size_t)NE * es;

    char* w = (char*)d_ws;
    auto alloc = [&](size_t bytes) { void* p = (void*)w; w += (bytes + 255) & ~(size_t)255; return p; };
    float* h      = (float*)alloc((size_t)NN * DD * 4);   // GEMM1 out; dead after agg ->
    float* part   = h;                                    //   pgemm partials [125][128][512] = 33MB
    float* g      = (float*)alloc((size_t)NN * DD * 4);   // conv1 out; before agg,
    short* xh     = (short*)g;                            //   aliased as xs bf16 hi
    short* xl     = (short*)g + (size_t)NN * DD;          //   and lo - dead after gemm
    short* W1h    = (short*)alloc((size_t)DD * DD * 2);
    short* W1l    = (short*)alloc((size_t)DD * DD * 2);
    float* Cf     = (float*)alloc((size_t)NG * NN * 4);   // pooling coeff matrix, 10.24MB
    float* pooled = (float*)alloc((size_t)NG * DD * 4);
    float* tbuf   = (float*)alloc((size_t)NG * DD * 4);
    float* inv_n  = (float*)alloc(NG * 4);
    float* rstd   = (float*)alloc(DD * 4);
    float* murs   = (float*)alloc(DD * 4);
    float* stats  = (float*)alloc(2 * DD * 4);
    float* dis    = (float*)alloc(NN * 4);
    int*   deg    = (int*)alloc(NN * 4);
    int*   rowptr = (int*)alloc((NN + 4) * 4);
    int*   cursor = (int*)alloc(NN * 4);
    int*   csrsrc = (int*)alloc(NE * 4);
    float* colsum = stats;
    float* colsq  = stats + DD;

    // scaler stats -> rstd, mu*rstd; standardize+split x, split W1^T
    hipMemsetAsync(stats, 0, 2 * DD * 4, stream);
    colstats_kernel<<<dim3(2, 200), 256, 0, stream>>>(x, colsum, colsq);
    finalize_kernel<<<1, 512, 0, stream>>>(colsum, colsq, rstd, murs);
    xsplit_kernel<<<10000, 256, 0, stream>>>(x, rstd, murs, xh, xl);
    wsplit_kernel<<<dim3(16, 16), 256, 0, stream>>>(W1, W1h, W1l);

    // graph structure
    deginit_kernel<<<(NN + 255) / 256, 256, 0, stream>>>(deg);
    degcount_kernel<<<NE / 256, 256, 0, stream>>>(edst, deg, es);
    dis_kernel<<<(NN + 255) / 256, 256, 0, stream>>>(deg, dis);
    scan_kernel<<<1, 1024, 0, stream>>>(deg, rowptr, cursor);
    scatter_kernel<<<NE / 256, 256, 0, stream>>>(esrc, edst, cursor, csrsrc, es);

    // pooling coefficient matrix + inv counts
    hipMemsetAsync(Cf, 0, (size_t)NG * NN * 4, stream);
    cnode_kernel<<<(NN + 255) / 256, 256, 0, stream>>>(batch, bs, dis, Cf);
    cedge_kernel<<<NE / 256, 256, 0, stream>>>(esrc, edst, es, batch, bs, dis, Cf);
    invn_kernel<<<1, NG, 0, stream>>>(batch, bs, inv_n);

    // conv1: h = xs @ W1 via split-bf16 MFMA (pipelined), then aggregate + b1 + relu -> g
    gemm_mfma_kernel<<<dim3((NN + 127) / 128, DD / 128), 256, 0, stream>>>(xh, xl, W1h, W1l, h, NN);
    agg_kernel<<<NN, 256, 0, stream>>>(h, g, dis, rowptr, csrsrc, b1, 1);
    // conv2+pool: pooled = diag(inv_n) * Cf @ g, as K-chunked streaming GEMM + reduce
    pgemm_kernel<<<dim3(4, PNC), 256, 0, stream>>>(Cf, g, part);
    reduce_kernel<<<1024, 64, 0, stream>>>(part, inv_n, pooled);
    // tail: out = ((pooled @ W2 + b2) @ Wlin + blin), parallel K-split GEMMs
    tail_kernel<<<dim3(NG, 8), 256, 0, stream>>>(pooled, W2, b2, tbuf);
    tail_kernel<<<dim3(NG, 8), 256, 0, stream>>>(tbuf, Wlin, blin, out);
}

// Round 14
// 339.538 us; speedup vs baseline: 1.2317x; 1.0374x over previous
//
#include <hip/hip_runtime.h>
#include <hip/hip_bf16.h>

// GCN forward: StandardScaler -> GCNConv(relu) -> GCNConv -> mean-pool -> Linear
// N=20000 nodes, E=160000 edges, D=512 all layers, G=128 graphs.
//
// Structure:
//  - xs = (x-mu)*rstd pre-split ONCE to bf16 hi/lo; GEMM1 = xs@W1 on matrix
//    cores, 3-term split-bf16, reg-staged pipeline; h written as bf16 (round 14)
//  - GEMM2 eliminated: out = pool(Agg(g)) @ W2 @ Wlin + (b2@Wlin+blin)
//  - pool(Agg(g)) = diag(1/n) * Cf * g with dense Cf[128x20000] (gather -> GEMM)
//  - agg gathers bf16 h (fetch halved); tail = reduce + two K-split GEMMs
//  - launch diet: single memset (Cf|stats|deg), cfbuild merged, dis+invn merged

#define NN 20000
#define NE 160000
#define DD 512
#define NG 128
#define PKC 160          // K per pgemm chunk (125 chunks * 160 = 20000 exactly)
#define PNC 125

typedef __attribute__((ext_vector_type(8))) short bf16x8;
typedef __attribute__((ext_vector_type(4))) float f32x4;

static __device__ __forceinline__ short f2bf(float f) {
    union { float f; unsigned u; } a; a.f = f;
    unsigned r = a.u + 0x7FFF + ((a.u >> 16) & 1);   // RNE
    return (short)(r >> 16);
}
static __device__ __forceinline__ float bf2f(short s) {
    union { unsigned u; float f; } a; a.u = ((unsigned)(unsigned short)s) << 16;
    return a.f;
}

// ---------------- column stats (mean / rstd) ----------------
__global__ __launch_bounds__(256) void colstats_kernel(const float* __restrict__ x,
                                                       float* __restrict__ colsum,
                                                       float* __restrict__ colsq) {
    int c = blockIdx.x * 256 + threadIdx.x;
    int r0 = blockIdx.y * 100;
    float s = 0.f, sq = 0.f;
    for (int r = r0; r < r0 + 100; ++r) {
        float v = x[(size_t)r * DD + c];
        s += v;
        sq = fmaf(v, v, sq);
    }
    atomicAdd(&colsum[c], s);
    atomicAdd(&colsq[c], sq);
}

__global__ void finalize_kernel(const float* __restrict__ colsum, const float* __restrict__ colsq,
                                float* __restrict__ rstd, float* __restrict__ murs) {
    int c = threadIdx.x;
    float m = colsum[c] * (1.0f / NN);
    float var = colsq[c] * (1.0f / NN) - m * m;
    float sd = sqrtf(fmaxf(var, 0.0f));
    float rs = (sd > 0.0f) ? (1.0f / sd) : 1.0f;
    rstd[c] = rs;
    murs[c] = m * rs;
}

// xs = x*rstd - murs, split to bf16 hi/lo. One float4 per thread.
__global__ __launch_bounds__(256) void xsplit_kernel(const float* __restrict__ x,
                                                     const float* __restrict__ rstd,
                                                     const float* __restrict__ murs,
                                                     short* __restrict__ xh,
                                                     short* __restrict__ xl) {
    int idx = blockIdx.x * 256 + threadIdx.x;
    int c4 = (idx & 127) * 4;
    float4 v = *(const float4*)(x + (size_t)idx * 4);
    float4 rs = *(const float4*)(rstd + c4);
    float4 ms = *(const float4*)(murs + c4);
    float s0 = fmaf(v.x, rs.x, -ms.x), s1 = fmaf(v.y, rs.y, -ms.y);
    float s2 = fmaf(v.z, rs.z, -ms.z), s3 = fmaf(v.w, rs.w, -ms.w);
    short h0 = f2bf(s0), h1 = f2bf(s1), h2 = f2bf(s2), h3 = f2bf(s3);
    *(short4*)(xh + (size_t)idx * 4) = make_short4(h0, h1, h2, h3);
    *(short4*)(xl + (size_t)idx * 4) =
        make_short4(f2bf(s0 - bf2f(h0)), f2bf(s1 - bf2f(h1)),
                    f2bf(s2 - bf2f(h2)), f2bf(s3 - bf2f(h3)));
}

// W^T bf16 split: Wh/Wl[n][k] = split(W1[k][n]); 32x32 LDS tiles
__global__ __launch_bounds__(256) void wsplit_kernel(const float* __restrict__ W1,
                                                     short* __restrict__ Wh,
                                                     short* __restrict__ Wl) {
    __shared__ float t[32][33];
    int bk = blockIdx.x * 32, bn = blockIdx.y * 32;
    int r = threadIdx.x >> 5, c = threadIdx.x & 31;
#pragma unroll
    for (int i = 0; i < 4; ++i) {
        int rr = r + i * 8;
        t[rr][c] = W1[(size_t)(bk + rr) * DD + bn + c];
    }
    __syncthreads();
#pragma unroll
    for (int i = 0; i < 4; ++i) {
        int rr = r + i * 8;
        float v = t[c][rr];
        short h = f2bf(v);
        short l = f2bf(v - bf2f(h));
        Wh[(size_t)(bn + rr) * DD + bk + c] = h;
        Wl[(size_t)(bn + rr) * DD + bk + c] = l;
    }
}

// ---------------- graph structure ----------------
// deg holds INDEG (memset 0 + edge count); self-loop handled as +1 at use sites.
__global__ void degcount_kernel(const int* __restrict__ dst, int* __restrict__ deg, int es) {
    int e = blockIdx.x * 256 + threadIdx.x;
    if (e < NE) {
        int d = dst[(size_t)e * es];
        if ((unsigned)d < (unsigned)NN) atomicAdd(&deg[d], 1);
    }
}

// blocks 0..78: dis[i] = rsqrt(indeg+1); block 79: inv_n per graph (batch sorted)
__global__ __launch_bounds__(256) void dis_invn_kernel(const int* __restrict__ deg,
                                                       float* __restrict__ dis,
                                                       const int* __restrict__ batch, int bs,
                                                       float* __restrict__ inv_n) {
    if (blockIdx.x < 79) {
        int i = blockIdx.x * 256 + threadIdx.x;
        if (i < NN) dis[i] = rsqrtf((float)(deg[i] + 1));
    } else {
        int g = threadIdx.x;
        if (g < NG) {
            int lo = 0, hi = NN;
            while (lo < hi) { int m = (lo + hi) >> 1; if (batch[(size_t)m * bs] < g) lo = m + 1; else hi = m; }
            int l0 = lo;
            lo = l0; hi = NN;
            while (lo < hi) { int m = (lo + hi) >> 1; if (batch[(size_t)m * bs] < g + 1) lo = m + 1; else hi = m; }
            inv_n[g] = 1.0f / fmaxf((float)(lo - l0), 1.0f);
        }
    }
}

// exclusive scan of indeg; writes rowptr[0..20000] and cursor copy
__global__ __launch_bounds__(1024) void scan_kernel(const int* __restrict__ deg,
                                                    int* __restrict__ rowptr,
                                                    int* __restrict__ cursor) {
    const int PER = 20;
    __shared__ int sums[1024];
    int t = threadIdx.x;
    int base = t * PER;
    int local[PER];
    int s = 0;
#pragma unroll
    for (int j = 0; j < PER; ++j) {
        int idx = base + j;
        int v = (idx < NN) ? deg[idx] : 0;
        local[j] = s;
        s += v;
    }
    sums[t] = s;
    __syncthreads();
    for (int off = 1; off < 1024; off <<= 1) {
        int v = (t >= off) ? sums[t - off] : 0;
        __syncthreads();
        sums[t] += v;
        __syncthreads();
    }
    int prefix = (t == 0) ? 0 : sums[t - 1];
#pragma unroll
    for (int j = 0; j < PER; ++j) {
        int idx = base + j;
        if (idx <= NN) {
            int val = prefix + local[j];
            rowptr[idx] = val;
            if (idx < NN) cursor[idx] = val;
        }
    }
}

__global__ void scatter_kernel(const int* __restrict__ src, const int* __restrict__ dst,
                               int* __restrict__ cursor, int* __restrict__ csrsrc, int es) {
    int e = blockIdx.x * 256 + threadIdx.x;
    if (e < NE) {
        int d = dst[(size_t)e * es];
        int sN = src[(size_t)e * es];
        if ((unsigned)d < (unsigned)NN && (unsigned)sN < (unsigned)NN) {
            int slot = atomicAdd(&cursor[d], 1);
            csrsrc[slot] = sN;
        }
    }
}

// ---------------- pooling coefficient matrix Cf[NG][NN] (node + edge passes merged) --------
__global__ void cfbuild_kernel(const int* __restrict__ src, const int* __restrict__ dst, int es,
                               const int* __restrict__ batch, int bs,
                               const float* __restrict__ dis, float* __restrict__ Cf) {
    int idx = blockIdx.x * 256 + threadIdx.x;
    if (idx < NN) {
        int G = batch[(size_t)idx * bs];
        if ((unsigned)G < (unsigned)NG) {
            float d = dis[idx];
            atomicAdd(&Cf[(size_t)G * NN + idx], d * d);
        }
    } else if (idx < NN + NE) {
        int e = idx - NN;
        int i = dst[(size_t)e * es];
        int s = src[(size_t)e * es];
        if ((unsigned)i < (unsigned)NN && (unsigned)s < (unsigned)NN) {
            int G = batch[(size_t)i * bs];
            if ((unsigned)G < (unsigned)NG)
                atomicAdd(&Cf[(size_t)G * NN + s], dis[i] * dis[s]);
        }
    }
}

// ---------------- split-bf16 MFMA GEMM: Ch[M x 512](bf16) = A @ W^T ----------------
__global__ __launch_bounds__(256) void gemm_mfma_kernel(const short* __restrict__ Ah_g,
                                                        const short* __restrict__ Al_g,
                                                        const short* __restrict__ Bh_g,
                                                        const short* __restrict__ Bl_g,
                                                        unsigned short* __restrict__ Ch,
                                                        int M) {
    __shared__ __attribute__((aligned(16))) short sAh[128][40];
    __shared__ __attribute__((aligned(16))) short sAl[128][40];
    __shared__ __attribute__((aligned(16))) short sBh[128][40];
    __shared__ __attribute__((aligned(16))) short sBl[128][40];
    int tid = threadIdx.x;
    int wave = tid >> 6, lane = tid & 63;
    int wm = (wave >> 1) * 64, wn = (wave & 1) * 64;
    int rowBase = blockIdx.x * 128, colBase = blockIdx.y * 128;
    int fr = lane & 15, kq = (lane >> 4) * 8;

    int s0 = tid, s1 = tid + 256;
    int r0 = s0 >> 2, k80 = (s0 & 3) * 8;
    int r1 = s1 >> 2, k81 = (s1 & 3) * 8;
    int ga0 = rowBase + r0, ga1 = rowBase + r1;
    int gb0 = colBase + r0, gb1 = colBase + r1;
    const bool av0 = ga0 < M, av1 = ga1 < M;

    f32x4 acc[4][4];
#pragma unroll
    for (int i = 0; i < 4; ++i)
#pragma unroll
        for (int j = 0; j < 4; ++j) acc[i][j] = (f32x4){0.f, 0.f, 0.f, 0.f};

    const bf16x8 z8 = {0, 0, 0, 0, 0, 0, 0, 0};
    bf16x8 rAh0, rAh1, rAl0, rAl1, rBh0, rBh1, rBl0, rBl1;

#define GLOAD(KK)                                                                      \
    do {                                                                               \
        rAh0 = av0 ? *(const bf16x8*)(Ah_g + (size_t)ga0 * DD + (KK) + k80) : z8;      \
        rAl0 = av0 ? *(const bf16x8*)(Al_g + (size_t)ga0 * DD + (KK) + k80) : z8;      \
        rAh1 = av1 ? *(const bf16x8*)(Ah_g + (size_t)ga1 * DD + (KK) + k81) : z8;      \
        rAl1 = av1 ? *(const bf16x8*)(Al_g + (size_t)ga1 * DD + (KK) + k81) : z8;      \
        rBh0 = *(const bf16x8*)(Bh_g + (size_t)gb0 * DD + (KK) + k80);                 \
        rBl0 = *(const bf16x8*)(Bl_g + (size_t)gb0 * DD + (KK) + k80);                 \
        rBh1 = *(const bf16x8*)(Bh_g + (size_t)gb1 * DD + (KK) + k81);                 \
        rBl1 = *(const bf16x8*)(Bl_g + (size_t)gb1 * DD + (KK) + k81);                 \
    } while (0)

    GLOAD(0);
    for (int step = 0; step < 16; ++step) {
        *(bf16x8*)&sAh[r0][k80] = rAh0;  *(bf16x8*)&sAl[r0][k80] = rAl0;
        *(bf16x8*)&sAh[r1][k81] = rAh1;  *(bf16x8*)&sAl[r1][k81] = rAl1;
        *(bf16x8*)&sBh[r0][k80] = rBh0;  *(bf16x8*)&sBl[r0][k80] = rBl0;
        *(bf16x8*)&sBh[r1][k81] = rBh1;  *(bf16x8*)&sBl[r1][k81] = rBl1;
        __syncthreads();
        if (step < 15) GLOAD((step + 1) * 32);

        bf16x8 fah[4], fal[4], fbh[4], fbl[4];
#pragma unroll
        for (int mi = 0; mi < 4; ++mi) {
            fah[mi] = *(const bf16x8*)&sAh[wm + mi * 16 + fr][kq];
            fal[mi] = *(const bf16x8*)&sAl[wm + mi * 16 + fr][kq];
        }
#pragma unroll
        for (int ni = 0; ni < 4; ++ni) {
            fbh[ni] = *(const bf16x8*)&sBh[wn + ni * 16 + fr][kq];
            fbl[ni] = *(const bf16x8*)&sBl[wn + ni * 16 + fr][kq];
        }
#pragma unroll
        for (int mi = 0; mi < 4; ++mi)
#pragma unroll
            for (int ni = 0; ni < 4; ++ni) {
                acc[mi][ni] = __builtin_amdgcn_mfma_f32_16x16x32_bf16(fah[mi], fbh[ni], acc[mi][ni], 0, 0, 0);
                acc[mi][ni] = __builtin_amdgcn_mfma_f32_16x16x32_bf16(fah[mi], fbl[ni], acc[mi][ni], 0, 0, 0);
                acc[mi][ni] = __builtin_amdgcn_mfma_f32_16x16x32_bf16(fal[mi], fbh[ni], acc[mi][ni], 0, 0, 0);
            }
        __syncthreads();
    }
#undef GLOAD

    // epilogue -> bf16 h: col = lane&15 grouping, row = (lane>>4)*4 + reg
#pragma unroll
    for (int mi = 0; mi < 4; ++mi)
#pragma unroll
        for (int ni = 0; ni < 4; ++ni) {
            int col = colBase + wn + ni * 16 + fr;
            int row0 = rowBase + wm + mi * 16 + (lane >> 4) * 4;
#pragma unroll
            for (int r = 0; r < 4; ++r) {
                int row = row0 + r;
                if (row < M) Ch[(size_t)row * DD + col] = (unsigned short)f2bf(acc[mi][ni][r]);
            }
        }
}

// ---------------- edge aggregation (bf16 h): out[i] = di*(di*h[i] + sum ds*h[s]) + b [relu] --
__global__ __launch_bounds__(256) void agg_kernel(const unsigned short* __restrict__ h,
                                                  float* __restrict__ out,
                                                  const float* __restrict__ dis,
                                                  const int* __restrict__ rowptr,
                                                  const int* __restrict__ csrsrc,
                                                  const float* __restrict__ bias,
                                                  int relu) {
    int i = blockIdx.x;
    int f = threadIdx.x * 2;
    float di = dis[i];
    ushort2 v = *(const ushort2*)(h + (size_t)i * DD + f);
    float accx = di * bf2f((short)v.x), accy = di * bf2f((short)v.y);
    int e0 = rowptr[i], e1 = rowptr[i + 1];
    if (e0 < e1) {
        int s = csrsrc[e0];
        float ds = dis[s];
        for (int e = e0; e < e1; ++e) {
            int   sn = 0;
            float dn = 0.f;
            if (e + 1 < e1) { sn = csrsrc[e + 1]; dn = dis[sn]; }
            ushort2 hv = *(const ushort2*)(h + (size_t)s * DD + f);
            accx = fmaf(ds, bf2f((short)hv.x), accx);
            accy = fmaf(ds, bf2f((short)hv.y), accy);
            s = sn; ds = dn;
        }
    }
    accx = fmaf(di, accx, bias[f]);
    accy = fmaf(di, accy, bias[f + 1]);
    if (relu) { accx = fmaxf(accx, 0.f); accy = fmaxf(accy, 0.f); }
    *(float2*)(out + (size_t)i * DD + f) = make_float2(accx, accy);
}

// ---------------- pooling GEMM: part[kc][128][512] = Cf[:, krange] @ g[krange, :] ----------
__global__ __launch_bounds__(256) void pgemm_kernel(const float* __restrict__ A,   // Cf [128][NN]
                                                    const float* __restrict__ B,   // g  [NN][512]
                                                    float* __restrict__ part) {
    __shared__ float As[16][132];
    __shared__ float Bs[16][128];
    int tid = threadIdx.x;
    int tx = tid & 15, ty = tid >> 4;
    int colBase = blockIdx.x * 128;
    int kc = blockIdx.y;
    int kBase = kc * PKC;

    float acc[8][8];
#pragma unroll
    for (int i = 0; i < 8; ++i)
#pragma unroll
        for (int j = 0; j < 8; ++j) acc[i][j] = 0.f;

    for (int k0 = kBase; k0 < kBase + PKC; k0 += 16) {
#pragma unroll
        for (int i = 0; i < 2; ++i) {
            int lin = tid + i * 256;
            int r = lin >> 2, c4 = (lin & 3) * 4;
            float4 v = *(const float4*)(A + (size_t)r * NN + k0 + c4);
            As[c4 + 0][r] = v.x;
            As[c4 + 1][r] = v.y;
            As[c4 + 2][r] = v.z;
            As[c4 + 3][r] = v.w;
        }
#pragma unroll
        for (int i = 0; i < 2; ++i) {
            int lin = tid + i * 256;
            int kk = lin >> 5, c4 = (lin & 31) * 4;
            *(float4*)&Bs[kk][c4] = *(const float4*)(B + (size_t)(k0 + kk) * DD + colBase + c4);
        }
        __syncthreads();
#pragma unroll
        for (int kk = 0; kk < 16; ++kk) {
            float a[8], b[8];
            *(float4*)&a[0] = *(const float4*)&As[kk][ty * 4];
            *(float4*)&a[4] = *(const float4*)&As[kk][64 + ty * 4];
            *(float4*)&b[0] = *(const float4*)&Bs[kk][tx * 4];
            *(float4*)&b[4] = *(const float4*)&Bs[kk][64 + tx * 4];
#pragma unroll
            for (int i = 0; i < 8; ++i)
#pragma unroll
                for (int j = 0; j < 8; ++j) acc[i][j] = fmaf(a[i], b[j], acc[i][j]);
        }
        __syncthreads();
    }

    float* dst = part + (size_t)kc * NG * DD;
#pragma unroll
    for (int i = 0; i < 8; ++i) {
        int r = (i < 4) ? (ty * 4 + i) : (64 + ty * 4 + (i - 4));
        int c0 = colBase + tx * 4;
        int c1c = colBase + 64 + tx * 4;
        *(float4*)(dst + (size_t)r * DD + c0) =
            make_float4(acc[i][0], acc[i][1], acc[i][2], acc[i][3]);
        *(float4*)(dst + (size_t)r * DD + c1c) =
            make_float4(acc[i][4], acc[i][5], acc[i][6], acc[i][7]);
    }
}

// ---------------- slice reduce: pooled[e] = inv_n[g] * sum_sl part[sl][e] ----------------
__global__ __launch_bounds__(64) void reduce_kernel(const float* __restrict__ part,
                                                    const float* __restrict__ inv_n,
                                                    float* __restrict__ pooled) {
    int e = blockIdx.x * 64 + threadIdx.x;
    float s = 0.f;
#pragma unroll 5
    for (int sl = 0; sl < PNC; ++sl)
        s += part[(size_t)sl * (NG * DD) + e];
    pooled[e] = s * inv_n[e >> 9];
}

// ---------------- tail GEMM: dst[g][col] = sum_k src[g][k]*W[k][col] + bias[col] ----------
__global__ __launch_bounds__(256) void tail_kernel(const float* __restrict__ src,  // [NG][DD]
                                                   const float* __restrict__ W,    // [DD][DD]
                                                   const float* __restrict__ bias,
                                                   float* __restrict__ dst) {
    __shared__ float p[DD];
    __shared__ float red[4][64];
    int g = blockIdx.x;
    int colBase = blockIdx.y * 64;
    int tid = threadIdx.x;
    int c = tid & 63, ks = tid >> 6;
    p[tid] = src[(size_t)g * DD + tid];
    p[tid + 256] = src[(size_t)g * DD + tid + 256];
    __syncthreads();
    int col = colBase + c;
    float acc = 0.f;
    int k0 = ks * 128;
#pragma unroll 8
    for (int k = k0; k < k0 + 128; ++k)
        acc = fmaf(p[k], W[(size_t)k * DD + col], acc);
    red[ks][c] = acc;
    __syncthreads();
    if (ks == 0)
        dst[(size_t)g * DD + col] = red[0][c] + red[1][c] + red[2][c] + red[3][c] + bias[col];
}

// ---------------- launch ----------------
extern "C" void kernel_launch(void* const* d_in, const int* in_sizes, int n_in,
                              void* d_out, int out_size, void* d_ws, size_t ws_size,
                              hipStream_t stream) {
    const float* x    = (const float*)d_in[0];
    const int*   ei   = (const int*)d_in[1];
    const int*   batch= (const int*)d_in[2];
    const float* W1   = (const float*)d_in[3];
    const float* b1   = (const float*)d_in[4];
    const float* W2   = (const float*)d_in[5];
    const float* b2   = (const float*)d_in[6];
    const float* Wlin = (const float*)d_in[7];
    const float* blin = (const float*)d_in[8];
    float* out = (float*)d_out;

    const int es = (in_sizes[1] == 2 * 2 * NE) ? 2 : 1;
    const int bs = (in_sizes[2] == 2 * NN) ? 2 : 1;
    const int* esrc = ei;
    const int* edst = ei + (size_t)NE * es;

    char* w = (char*)d_ws;
    auto alloc = [&](size_t bytes) { void* p = (void*)w; w += (bytes + 255) & ~(size_t)255; return p; };
    float* hreg   = (float*)alloc((size_t)NN * DD * 4);   // region: bf16 h (20.5MB), later part (33MB)
    unsigned short* hb = (unsigned short*)hreg;
    float* part   = hreg;
    float* g      = (float*)alloc((size_t)NN * DD * 4);   // conv1 out; before agg aliased as xs
    short* xh     = (short*)g;
    short* xl     = (short*)g + (size_t)NN * DD;
    short* W1h    = (short*)alloc((size_t)DD * DD * 2);
    short* W1l    = (short*)alloc((size_t)DD * DD * 2);
    // --- zero-init region: Cf | stats | deg  (one memset) ---
    float* Cf     = (float*)alloc((size_t)NG * NN * 4);   // 10.24MB
    float* stats  = (float*)alloc(2 * DD * 4);
    int*   deg    = (int*)alloc(NN * 4);
    size_t zbytes = (size_t)((char*)deg + (size_t)NN * 4 - (char*)Cf);
    // --------------------------------------------------------
    float* pooled = (float*)alloc((size_t)NG * DD * 4);
    float* tbuf   = (float*)alloc((size_t)NG * DD * 4);
    float* inv_n  = (float*)alloc(NG * 4);
    float* rstd   = (float*)alloc(DD * 4);
    float* murs   = (float*)alloc(DD * 4);
    float* dis    = (float*)alloc(NN * 4);
    int*   rowptr = (int*)alloc((NN + 4) * 4);
    int*   cursor = (int*)alloc(NN * 4);
    int*   csrsrc = (int*)alloc(NE * 4);
    float* colsum = stats;
    float* colsq  = stats + DD;

    // one memset covers Cf + stats + deg
    hipMemsetAsync(Cf, 0, zbytes, stream);
    // scaler stats -> rstd, mu*rstd; standardize+split x, split W1^T
    colstats_kernel<<<dim3(2, 200), 256, 0, stream>>>(x, colsum, colsq);
    finalize_kernel<<<1, 512, 0, stream>>>(colsum, colsq, rstd, murs);
    xsplit_kernel<<<10000, 256, 0, stream>>>(x, rstd, murs, xh, xl);
    wsplit_kernel<<<dim3(16, 16), 256, 0, stream>>>(W1, W1h, W1l);

    // graph structure (deg = indeg)
    degcount_kernel<<<NE / 256, 256, 0, stream>>>(edst, deg, es);
    dis_invn_kernel<<<80, 256, 0, stream>>>(deg, dis, batch, bs, inv_n);
    scan_kernel<<<1, 1024, 0, stream>>>(deg, rowptr, cursor);
    scatter_kernel<<<NE / 256, 256, 0, stream>>>(esrc, edst, cursor, csrsrc, es);

    // pooling coefficient matrix (node + edge contributions)
    cfbuild_kernel<<<(NN + NE + 255) / 256, 256, 0, stream>>>(esrc, edst, es, batch, bs, dis, Cf);

    // conv1: h(bf16) = xs @ W1 via split-bf16 MFMA, then aggregate + b1 + relu -> g
    gemm_mfma_kernel<<<dim3((NN + 127) / 128, DD / 128), 256, 0, stream>>>(xh, xl, W1h, W1l, hb, NN);
    agg_kernel<<<NN, 256, 0, stream>>>(hb, g, dis, rowptr, csrsrc, b1, 1);
    // conv2+pool: pooled = diag(inv_n) * Cf @ g  (h dead -> part aliases it)
    pgemm_kernel<<<dim3(4, PNC), 256, 0, stream>>>(Cf, g, part);
    reduce_kernel<<<1024, 64, 0, stream>>>(part, inv_n, pooled);
    // tail: out = ((pooled @ W2 + b2) @ Wlin + blin)
    tail_kernel<<<dim3(NG, 8), 256, 0, stream>>>(pooled, W2, b2, tbuf);
    tail_kernel<<<dim3(NG, 8), 256, 0, stream>>>(tbuf, Wlin, blin, out);
}